// Round 5
// baseline (652.628 us; speedup 1.0000x reference)
//
#include <hip/hip_runtime.h>
#include <hip/hip_bf16.h>

typedef __hip_bfloat16 bf16;
typedef __attribute__((ext_vector_type(8))) short short8;
typedef __attribute__((ext_vector_type(4))) short s16x4;
typedef __attribute__((ext_vector_type(4))) float f32x4;

__device__ __forceinline__ bf16 f2b(float f) { return __float2bfloat16(f); }
__device__ __forceinline__ short bfbits(float f) {
  union { float f; unsigned u; } x; x.f = f;
  unsigned r = x.u + 0x7fff + ((x.u >> 16) & 1);  // RNE
  return (short)(r >> 16);
}
// tanh(x) = sign(x) * (1-t)/(1+t), t = e^{-2|x|}  — ~8 VALU ops, err ~1e-6
__device__ __forceinline__ float tanh_fast(float x) {
  float t = __expf(-2.f * fabsf(x));
  float r = (1.f - t) * __builtin_amdgcn_rcpf(1.f + t);
  return copysignf(r, x);
}

#define BM 128
#define BN 128
#define BK 32

#define GLOAD_LDS16(gp, lp) __builtin_amdgcn_global_load_lds( \
    (const __attribute__((address_space(1))) void*)(gp), \
    (__attribute__((address_space(3))) void*)(lp), 16, 0, 0)

// ---------------- prep: bf16 weight layouts (coalesced transpose) ----------
__global__ __launch_bounds__(256) void prep(
    const float* __restrict__ W2, const float* __restrict__ Wf2,
    const float* __restrict__ W1, const float* __restrict__ Wff,
    bf16* __restrict__ W2bf, bf16* __restrict__ W2Tbf,
    bf16* __restrict__ Wf2bf, bf16* __restrict__ W1n,
    bf16* __restrict__ Wffn)
{
  __shared__ float T[32][33];
  const int tid = threadIdx.x, bx = blockIdx.x;
  const int tx = bx & 31, ty = bx >> 5;
  const int r = tid >> 3, c4 = (tid & 7) * 4;
  const long ibase = (long)(ty * 32 + r) * 1024 + tx * 32 + c4;

  f32x4 v = *(const f32x4*)(W2 + ibase);
  f32x4 vf = *(const f32x4*)(Wf2 + ibase);
  s16x4 sv, sf;
  #pragma unroll
  for (int j = 0; j < 4; ++j) {
    sv[j] = bfbits(v[j]); sf[j] = bfbits(vf[j]);
    T[r][c4 + j] = v[j];
  }
  *(s16x4*)(W2bf + ibase) = sv;
  *(s16x4*)(Wf2bf + ibase) = sf;
  __syncthreads();
  const int oc = tid >> 3, or4 = (tid & 7) * 4;
  s16x4 st;
  #pragma unroll
  for (int j = 0; j < 4; ++j) st[j] = bfbits(T[or4 + j][oc]);
  *(s16x4*)(W2Tbf + (long)(tx * 32 + oc) * 1024 + ty * 32 + or4) = st;

  if (bx < 32) {  // W1n (16x1024, transpose of W1) + Wffn (straight)
    #pragma unroll
    for (int rep = 0; rep < 2; ++rep) {
      int i = bx * 512 + rep * 256 + tid;
      int rr = i >> 10, cc = i & 1023;
      W1n[i] = f2b(W1[cc * 16 + rr]);
      Wffn[i] = f2b(Wff[i]);
    }
  }
}

// ---------------- K1: h1 = tanh(z @ W1^T + b1) ----------------
__global__ __launch_bounds__(256) void k1(
    const float* __restrict__ z, const float* __restrict__ W1,
    const float* __restrict__ b1, bf16* __restrict__ h1, long grow0)
{
  __shared__ float zs[32][16];
  const int tid = threadIdx.x;
  const long r0 = (long)blockIdx.x * 32;
  for (int i = tid; i < 512; i += 256) {
    int r = i >> 4, c = i & 15;
    zs[r][c] = z[(grow0 + r0 + r) * 16 + c];
  }
  __syncthreads();
  #pragma unroll
  for (int jj = 0; jj < 4; ++jj) {
    const int c = tid + jj * 256;
    float w[16];
    #pragma unroll
    for (int k = 0; k < 16; ++k) w[k] = W1[c * 16 + k];
    const float bc = b1[c];
    for (int r = 0; r < 32; ++r) {
      float a = bc;
      #pragma unroll
      for (int k = 0; k < 16; ++k) a = fmaf(zs[r][k], w[k], a);
      h1[(r0 + r) * 1024 + c] = f2b(tanh_fast(a));
    }
  }
}

// ---------------- MFMA GEMM + fused epilogues ------------------------------
// C = A[CKx1024] * B (Bp[n][k] layout). LDS k-chunk swizzle (T2 both-sides).
// EPI 0 (gemm0): x=a2. h2=tanh(x+b2); s1=1-h2^2; O2=gb=s1*Wh[c];
//                f1 = zu@Wf1^T (staged LDS); O1=g1f=tanh(f1)+f1*s1.
// EPI 1 (gemm1): g1b = x*(1-h1^2) -> Ot(LDS) -> project @W1n^T -> Pp partials
// EPI 2 (gemm2): f=x+bf2; g2f=tanh(f)+f*(1-h1^2) -> Ot -> @Wffn^T -> Pp
template<int EPI>
__global__ __launch_bounds__(256) void gemm_k(
    const bf16* __restrict__ A, const bf16* __restrict__ Bp,
    const float* __restrict__ bias, const float* __restrict__ Whv,
    const bf16* __restrict__ h1, bf16* __restrict__ O1, bf16* __restrict__ O2,
    const float* __restrict__ z, const float* __restrict__ Wp,
    const float* __restrict__ bp, const float* __restrict__ Wf1,
    const float* __restrict__ bf1v, const bf16* __restrict__ Wn,
    float* __restrict__ Pp, long grow0, int ckRows)
{
  constexpr int SMEM = (EPI == 0) ? 37888 : 34816;
  __shared__ __align__(16) char smem[SMEM];
  bf16* As = (bf16*)smem;
  bf16* Bs = (bf16*)(smem + 8192);
  const int tid = threadIdx.x;
  const int lane = tid & 63, wid = tid >> 6;
  const int wr = wid >> 1, wc = wid & 1;
  const int fr = lane & 15, kg = lane >> 4;
  const long row0 = (long)blockIdx.x * BM;
  const int col0 = blockIdx.y * BN;

  const int sr0 = tid >> 2;                            // staging row in tile
  const int sk0 = ((tid & 3) ^ ((tid >> 3) & 3)) * 8;  // pre-swizzled k-chunk
  const int swr = (fr >> 1) & 3;                       // read-side XOR term

  float* zs = (float*)(smem + 16384);   // [128][17]
  float* us = (float*)(smem + 25088);   // [128][5]
  float* wf = (float*)(smem + 27648);   // [128][20]
  if (EPI == 0) {
    for (int i = tid; i < 2048; i += 256) {
      int r = i >> 4, c = i & 15;
      zs[r * 17 + c] = z[(grow0 + row0 + r) * 16 + c];
    }
    for (int i = tid; i < 2560; i += 256) {
      int c = i / 20, k = i - c * 20;
      wf[c * 20 + k] = Wf1[(col0 + c) * 20 + k];
    }
    __syncthreads();
    for (int i = tid; i < 512; i += 256) {
      int r = i >> 2, a = i & 3;
      float acc = bp[a];
      #pragma unroll
      for (int k = 0; k < 16; ++k) acc = fmaf(zs[r * 17 + k], Wp[a * 16 + k], acc);
      us[r * 5 + a] = tanh_fast(acc);
    }
    // main-loop __syncthreads covers the us barrier (first staging+sync below)
  }

  f32x4 acc[4][4];
  #pragma unroll
  for (int m = 0; m < 4; ++m)
    #pragma unroll
    for (int n = 0; n < 4; ++n) acc[m][n] = (f32x4){0.f, 0.f, 0.f, 0.f};

  for (int kt = 0; kt < 1024 / BK; ++kt) {
    const int k0 = kt * BK;
    if (EPI == 0 && kt == 0) __syncthreads();  // us ready before As reuse? (independent regions; this orders us-writes vs epilogue reads)
    #pragma unroll
    for (int it = 0; it < 2; ++it) {
      const bf16* ga = A + (row0 + sr0 + it * 64) * 1024 + (k0 + sk0);
      GLOAD_LDS16(ga, As + it * 2048 + tid * 8);
      const bf16* gbp = Bp + (long)(col0 + sr0 + it * 64) * 1024 + (k0 + sk0);
      GLOAD_LDS16(gbp, Bs + it * 2048 + tid * 8);
    }
    __syncthreads();
    short8 af[4], bfr[4];
    #pragma unroll
    for (int m = 0; m < 4; ++m)
      af[m] = *(const short8*)(As + (wr * 64 + m * 16 + fr) * 32 + (kg ^ swr) * 8);
    #pragma unroll
    for (int n = 0; n < 4; ++n)
      bfr[n] = *(const short8*)(Bs + (wc * 64 + n * 16 + fr) * 32 + (kg ^ swr) * 8);
    #pragma unroll
    for (int m = 0; m < 4; ++m)
      #pragma unroll
      for (int n = 0; n < 4; ++n)
        acc[m][n] = __builtin_amdgcn_mfma_f32_16x16x32_bf16(af[m], bfr[n], acc[m][n], 0, 0, 0);
    __syncthreads();
  }

  bf16* Ot = (bf16*)smem;  // [128][136] bf16, reuses As/Bs post-loop
  #pragma unroll
  for (int m = 0; m < 4; ++m) {
    const int rl0 = wr * 64 + m * 16 + kg * 4;
    const long gr0 = row0 + rl0;
    #pragma unroll
    for (int n = 0; n < 4; ++n) {
      const int cl = wc * 64 + n * 16 + fr;
      const int gc = col0 + cl;
      f32x4 v = acc[m][n];
      #pragma unroll
      for (int j = 0; j < 4; ++j) {
        const long idx = (gr0 + j) * 1024 + gc;
        float x = v[j];
        if (EPI == 0) {
          float h = tanh_fast(x + bias[gc]);
          float s1v = 1.f - h * h;
          O2[idx] = f2b(s1v * Whv[gc]);
          const int rl = rl0 + j;
          float f = bf1v[gc];
          #pragma unroll
          for (int k = 0; k < 16; ++k) f = fmaf(zs[rl * 17 + k], wf[cl * 20 + k], f);
          #pragma unroll
          for (int a = 0; a < 4; ++a) f = fmaf(us[rl * 5 + a], wf[cl * 20 + 16 + a], f);
          O1[idx] = f2b(tanh_fast(f) + f * s1v);
        } else if (EPI == 1) {
          float hh = __bfloat162float(h1[idx]);
          Ot[(rl0 + j) * 136 + cl] = f2b(x * (1.f - hh * hh));
        } else {
          float f = x + bias[gc];
          float hh = __bfloat162float(h1[idx]);
          Ot[(rl0 + j) * 136 + cl] = f2b(tanh_fast(f) + f * (1.f - hh * hh));
        }
      }
    }
  }

  if (EPI != 0) {  // projection: P[128][16] = Ot @ Wn^T over this col-block
    __syncthreads();
    #pragma unroll
    for (int sub = 0; sub < 2; ++sub) {
      const int rl0 = wid * 32 + sub * 16;
      f32x4 pacc = (f32x4){0.f, 0.f, 0.f, 0.f};
      #pragma unroll
      for (int ks = 0; ks < 4; ++ks) {
        short8 afrag = *(const short8*)(Ot + (rl0 + fr) * 136 + ks * 32 + kg * 8);
        short8 bfrag = *(const short8*)(Wn + fr * 1024 + col0 + ks * 32 + kg * 8);
        pacc = __builtin_amdgcn_mfma_f32_16x16x32_bf16(afrag, bfrag, pacc, 0, 0, 0);
      }
      #pragma unroll
      for (int j = 0; j < 4; ++j)
        Pp[((long)blockIdx.y * ckRows + row0 + rl0 + kg * 4 + j) * 16 + fr] = pacc[j];
    }
  }
}

// ---------------- k7: out = J*(sum_cb(Pp0+Pp1) + bff) ----------------------
__global__ __launch_bounds__(256) void k7(
    const float* __restrict__ Pp0, const float* __restrict__ Pp1,
    const float* __restrict__ bff, float* __restrict__ out,
    long grow0, int ckRows)
{
  int i = blockIdx.x * 256 + threadIdx.x;
  int r = i >> 4, j = i & 15, jp = (j + 8) & 15;
  float s = bff[jp];
  #pragma unroll
  for (int cb = 0; cb < 8; ++cb) {
    long o = ((long)cb * ckRows + r) * 16 + jp;
    s += Pp0[o] + Pp1[o];
  }
  out[(grow0 + r) * 16 + j] = (j < 8) ? s : -s;
}

// ---------------- host ----------------
extern "C" void kernel_launch(void* const* d_in, const int* in_sizes, int n_in,
                              void* d_out, int out_size, void* d_ws, size_t ws_size,
                              hipStream_t stream) {
  const float* z   = (const float*)d_in[1];
  const float* W1  = (const float*)d_in[2];
  const float* b1  = (const float*)d_in[3];
  const float* W2  = (const float*)d_in[4];
  const float* b2  = (const float*)d_in[5];
  const float* Wh  = (const float*)d_in[6];
  const float* Wf1 = (const float*)d_in[8];
  const float* bf1 = (const float*)d_in[9];
  const float* Wf2 = (const float*)d_in[10];
  const float* bf2 = (const float*)d_in[11];
  const float* Wff = (const float*)d_in[12];
  const float* bff = (const float*)d_in[13];
  const float* Wp  = (const float*)d_in[14];
  const float* bp  = (const float*)d_in[15];
  float* out = (float*)d_out;
  const int N = in_sizes[1] / 16;

  char* p = (char*)d_ws;
  auto alloc = [&](size_t bytes) {
    char* q = p; p += (bytes + 255) & ~(size_t)255; return q;
  };
  bf16* W2bf  = (bf16*)alloc(1024 * 1024 * 2);
  bf16* W2Tbf = (bf16*)alloc(1024 * 1024 * 2);
  bf16* Wf2bf = (bf16*)alloc(1024 * 1024 * 2);
  bf16* W1n   = (bf16*)alloc(16 * 1024 * 2);
  bf16* Wffn  = (bf16*)alloc(16 * 1024 * 2);
  size_t wbytes = (size_t)(p - (char*)d_ws);

  int CK = N;  // chunk rows (power of two, divides N)
  // per-row: 3 bf16 act buffers (3*2048 B) + 2 Pp f32 partial sets (2*512 B)
  while (CK > 128 && wbytes + (size_t)CK * 7168 > ws_size) CK >>= 1;
  bf16* actA = (bf16*)alloc((size_t)CK * 2048);          // h1
  bf16* actB = (bf16*)alloc((size_t)CK * 2048);          // gb
  bf16* actD = (bf16*)alloc((size_t)CK * 2048);          // g1f
  float* Pp0 = (float*)alloc((size_t)CK * 8 * 16 * 4);   // gemm1 partials
  float* Pp1 = (float*)alloc((size_t)CK * 8 * 16 * 4);   // gemm2 partials

  prep<<<1024, 256, 0, stream>>>(W2, Wf2, W1, Wff, W2bf, W2Tbf, Wf2bf, W1n, Wffn);

  for (long r0 = 0; r0 < N; r0 += CK) {
    k1<<<CK / 32, 256, 0, stream>>>(z, W1, b1, actA, r0);
    gemm_k<0><<<dim3(CK / 128, 8), 256, 0, stream>>>(
        actA, W2bf, b2, Wh, nullptr, actD, actB,
        z, Wp, bp, Wf1, bf1, nullptr, nullptr, r0, CK);
    gemm_k<1><<<dim3(CK / 128, 8), 256, 0, stream>>>(
        actB, W2Tbf, nullptr, nullptr, actA, nullptr, nullptr,
        nullptr, nullptr, nullptr, nullptr, nullptr, W1n, Pp0, r0, CK);
    gemm_k<2><<<dim3(CK / 128, 8), 256, 0, stream>>>(
        actD, Wf2bf, bf2, nullptr, actA, nullptr, nullptr,
        nullptr, nullptr, nullptr, nullptr, nullptr, Wffn, Pp1, r0, CK);
    k7<<<CK / 16, 256, 0, stream>>>(Pp0, Pp1, bff, out, r0, CK);
  }
}

// Round 6
// 388.569 us; speedup vs baseline: 1.6796x; 1.6796x over previous
//
#include <hip/hip_runtime.h>
#include <hip/hip_bf16.h>

typedef __hip_bfloat16 bf16;
typedef __attribute__((ext_vector_type(8))) short short8;
typedef __attribute__((ext_vector_type(4))) short s16x4;
typedef __attribute__((ext_vector_type(4))) float f32x4;

__device__ __forceinline__ bf16 f2b(float f) { return __float2bfloat16(f); }
__device__ __forceinline__ short bfbits(float f) {
  union { float f; unsigned u; } x; x.f = f;
  unsigned r = x.u + 0x7fff + ((x.u >> 16) & 1);  // RNE
  return (short)(r >> 16);
}
// tanh(x) = sign(x) * (1-t)/(1+t), t = e^{-2|x|}  — ~8 VALU ops, err ~1e-6
__device__ __forceinline__ float tanh_fast(float x) {
  float t = __expf(-2.f * fabsf(x));
  float r = (1.f - t) * __builtin_amdgcn_rcpf(1.f + t);
  return copysignf(r, x);
}

#define BM 128
#define BN 128
#define BK 32

#define GLOAD_LDS16(gp, lp) __builtin_amdgcn_global_load_lds( \
    (const __attribute__((address_space(1))) void*)(gp), \
    (__attribute__((address_space(3))) void*)(lp), 16, 0, 0)

// ---------------- prep: bf16 weight layouts (coalesced transpose) ----------
// W2bf[n][k]=W2[n][k]; W2Tbf[n][k]=W2[k][n]; Wf2bf[n][k]=Wf2[n][k];
// W1n[j][k]=W1[k][j]; Wffn[j][k]=Wff[j][k]; Wf1p[n][k]=Wf1[n][k] (k<20, 0-pad to 32)
__global__ __launch_bounds__(256) void prep(
    const float* __restrict__ W2, const float* __restrict__ Wf2,
    const float* __restrict__ W1, const float* __restrict__ Wff,
    const float* __restrict__ Wf1,
    bf16* __restrict__ W2bf, bf16* __restrict__ W2Tbf,
    bf16* __restrict__ Wf2bf, bf16* __restrict__ W1n,
    bf16* __restrict__ Wffn, bf16* __restrict__ Wf1p)
{
  __shared__ float T[32][33];
  const int tid = threadIdx.x, bx = blockIdx.x;
  const int tx = bx & 31, ty = bx >> 5;
  const int r = tid >> 3, c4 = (tid & 7) * 4;
  const long ibase = (long)(ty * 32 + r) * 1024 + tx * 32 + c4;

  f32x4 v = *(const f32x4*)(W2 + ibase);
  f32x4 vf = *(const f32x4*)(Wf2 + ibase);
  s16x4 sv, sf;
  #pragma unroll
  for (int j = 0; j < 4; ++j) {
    sv[j] = bfbits(v[j]); sf[j] = bfbits(vf[j]);
    T[r][c4 + j] = v[j];
  }
  *(s16x4*)(W2bf + ibase) = sv;
  *(s16x4*)(Wf2bf + ibase) = sf;
  __syncthreads();
  const int oc = tid >> 3, or4 = (tid & 7) * 4;
  s16x4 st;
  #pragma unroll
  for (int j = 0; j < 4; ++j) st[j] = bfbits(T[or4 + j][oc]);
  *(s16x4*)(W2Tbf + (long)(tx * 32 + oc) * 1024 + ty * 32 + or4) = st;

  if (bx < 32) {  // W1n (16x1024, transpose of W1) + Wffn (straight)
    #pragma unroll
    for (int rep = 0; rep < 2; ++rep) {
      int i = bx * 512 + rep * 256 + tid;
      int rr = i >> 10, cc = i & 1023;
      W1n[i] = f2b(W1[cc * 16 + rr]);
      Wffn[i] = f2b(Wff[i]);
    }
  }
  if (bx < 128) {  // Wf1p: 1024x32, zero-padded K
    int i = bx * 256 + tid;
    int n = i >> 5, k = i & 31;
    Wf1p[i] = f2b(k < 20 ? Wf1[n * 20 + k] : 0.f);
  }
}

// ---------------- K1: h1 = tanh(z @ W1^T + b1) ----------------
__global__ __launch_bounds__(256) void k1(
    const float* __restrict__ z, const float* __restrict__ W1,
    const float* __restrict__ b1, bf16* __restrict__ h1, long grow0)
{
  __shared__ float zs[32][16];
  const int tid = threadIdx.x;
  const long r0 = (long)blockIdx.x * 32;
  for (int i = tid; i < 512; i += 256) {
    int r = i >> 4, c = i & 15;
    zs[r][c] = z[(grow0 + r0 + r) * 16 + c];
  }
  __syncthreads();
  #pragma unroll
  for (int jj = 0; jj < 4; ++jj) {
    const int c = tid + jj * 256;
    float w[16];
    #pragma unroll
    for (int k = 0; k < 16; ++k) w[k] = W1[c * 16 + k];
    const float bc = b1[c];
    for (int r = 0; r < 32; ++r) {
      float a = bc;
      #pragma unroll
      for (int k = 0; k < 16; ++k) a = fmaf(zs[r][k], w[k], a);
      h1[(r0 + r) * 1024 + c] = f2b(tanh_fast(a));
    }
  }
}

// ---------------- MFMA GEMM + fused epilogues ------------------------------
// C = A[CKx1024] * B (Bp[n][k] layout). LDS k-chunk swizzle (T2 both-sides).
// EPI 0 (gemm0): x=a2. h2=tanh(x+b2); s1=1-h2^2; O2=gb=s1*Wh[c];
//                f1 via ONE extra MFMA K-step (zu, Wf1p staged in LDS);
//                O1=g1f=tanh(f1)+f1*s1.
// EPI 1 (gemm1): g1b = x*(1-h1^2) -> Ot(LDS) -> project @W1n^T -> Pp partials
// EPI 2 (gemm2): f=x+bf2; g2f=tanh(f)+f*(1-h1^2) -> Ot -> @Wffn^T -> Pp
template<int EPI>
__global__ __launch_bounds__(256) void gemm_k(
    const bf16* __restrict__ A, const bf16* __restrict__ Bp,
    const float* __restrict__ bias, const float* __restrict__ Whv,
    const bf16* __restrict__ h1, bf16* __restrict__ O1, bf16* __restrict__ O2,
    const float* __restrict__ z, const float* __restrict__ Wp,
    const float* __restrict__ bp, const float* __restrict__ bf1v,
    const bf16* __restrict__ Wf1p, const bf16* __restrict__ Wn,
    float* __restrict__ Pp, long grow0, int ckRows)
{
  constexpr int SMEM = (EPI == 0) ? 16384 : 34816;
  __shared__ __align__(16) char smem[SMEM];
  bf16* As = (bf16*)smem;
  bf16* Bs = (bf16*)(smem + 8192);
  const int tid = threadIdx.x;
  const int lane = tid & 63, wid = tid >> 6;
  const int wr = wid >> 1, wc = wid & 1;
  const int fr = lane & 15, kg = lane >> 4;
  const long row0 = (long)blockIdx.x * BM;
  const int col0 = blockIdx.y * BN;

  const int sr0 = tid >> 2;                            // staging row in tile
  const int sk0 = ((tid & 3) ^ ((tid >> 3) & 3)) * 8;  // pre-swizzled k-chunk
  const int swr = (fr >> 1) & 3;                       // read-side XOR term

  f32x4 acc[4][4];
  #pragma unroll
  for (int m = 0; m < 4; ++m)
    #pragma unroll
    for (int n = 0; n < 4; ++n) acc[m][n] = (f32x4){0.f, 0.f, 0.f, 0.f};

  for (int kt = 0; kt < 1024 / BK; ++kt) {
    const int k0 = kt * BK;
    #pragma unroll
    for (int it = 0; it < 2; ++it) {
      const bf16* ga = A + (row0 + sr0 + it * 64) * 1024 + (k0 + sk0);
      GLOAD_LDS16(ga, As + it * 2048 + tid * 8);
      const bf16* gbp = Bp + (long)(col0 + sr0 + it * 64) * 1024 + (k0 + sk0);
      GLOAD_LDS16(gbp, Bs + it * 2048 + tid * 8);
    }
    __syncthreads();
    short8 af[4], bfr[4];
    #pragma unroll
    for (int m = 0; m < 4; ++m)
      af[m] = *(const short8*)(As + (wr * 64 + m * 16 + fr) * 32 + (kg ^ swr) * 8);
    #pragma unroll
    for (int n = 0; n < 4; ++n)
      bfr[n] = *(const short8*)(Bs + (wc * 64 + n * 16 + fr) * 32 + (kg ^ swr) * 8);
    #pragma unroll
    for (int m = 0; m < 4; ++m)
      #pragma unroll
      for (int n = 0; n < 4; ++n)
        acc[m][n] = __builtin_amdgcn_mfma_f32_16x16x32_bf16(af[m], bfr[n], acc[m][n], 0, 0, 0);
    __syncthreads();
  }

  if (EPI == 0) {
    // Stage zu (z|u|0-pad, K=32) and Wf1p tile; f1 = zu @ Wf1p^T via MFMA.
    bf16* zus = (bf16*)smem;           // [128][32]
    bf16* wfs = (bf16*)(smem + 8192);  // [128][32]
    for (int i = tid; i < 2048; i += 256) {
      int r = i >> 4, c = i & 15;
      zus[r * 32 + c] = f2b(z[(grow0 + row0 + r) * 16 + c]);
    }
    for (int i = tid; i < 1536; i += 256) {
      int r = i / 12, c = 20 + (i - (i / 12) * 12);
      zus[r * 32 + c] = f2b(0.f);
    }
    {
      const int r = tid >> 1;
      #pragma unroll
      for (int aa = 0; aa < 2; ++aa) {
        const int a = (tid & 1) * 2 + aa;
        float uacc = bp[a];
        #pragma unroll
        for (int k = 0; k < 16; ++k)
          uacc = fmaf(z[(grow0 + row0 + r) * 16 + k], Wp[a * 16 + k], uacc);
        zus[r * 32 + 16 + a] = f2b(tanh_fast(uacc));
      }
    }
    #pragma unroll
    for (int ps = 0; ps < 2; ++ps)
      GLOAD_LDS16(Wf1p + (long)col0 * 32 + ps * 2048 + tid * 8,
                  wfs + ps * 2048 + tid * 8);
    __syncthreads();
    short8 azu[4];
    #pragma unroll
    for (int m = 0; m < 4; ++m)
      azu[m] = *(const short8*)(zus + (wr * 64 + m * 16 + fr) * 32 + kg * 8);
    #pragma unroll
    for (int n = 0; n < 4; ++n) {
      const short8 bwf = *(const short8*)(wfs + (wc * 64 + n * 16 + fr) * 32 + kg * 8);
      const int gc = col0 + wc * 64 + n * 16 + fr;
      const float b2c = bias[gc], whc = Whv[gc], bfc = bf1v[gc];
      #pragma unroll
      for (int m = 0; m < 4; ++m) {
        f32x4 f1a = __builtin_amdgcn_mfma_f32_16x16x32_bf16(
            azu[m], bwf, (f32x4){0.f, 0.f, 0.f, 0.f}, 0, 0, 0);
        const long gr0 = row0 + wr * 64 + m * 16 + kg * 4;
        f32x4 v = acc[m][n];
        #pragma unroll
        for (int j = 0; j < 4; ++j) {
          const long idx = (gr0 + j) * 1024 + gc;
          float h = tanh_fast(v[j] + b2c);
          float s1v = 1.f - h * h;
          float f = f1a[j] + bfc;
          O2[idx] = f2b(s1v * whc);
          O1[idx] = f2b(tanh_fast(f) + f * s1v);
        }
      }
    }
  } else {
    bf16* Ot = (bf16*)smem;  // [128][136] bf16, reuses As/Bs post-loop
    #pragma unroll
    for (int m = 0; m < 4; ++m) {
      const int rl0 = wr * 64 + m * 16 + kg * 4;
      const long gr0 = row0 + rl0;
      #pragma unroll
      for (int n = 0; n < 4; ++n) {
        const int cl = wc * 64 + n * 16 + fr;
        const int gc = col0 + cl;
        f32x4 v = acc[m][n];
        #pragma unroll
        for (int j = 0; j < 4; ++j) {
          const long idx = (gr0 + j) * 1024 + gc;
          float x = v[j];
          if (EPI == 1) {
            float hh = __bfloat162float(h1[idx]);
            Ot[(rl0 + j) * 136 + cl] = f2b(x * (1.f - hh * hh));
          } else {
            float f = x + bias[gc];
            float hh = __bfloat162float(h1[idx]);
            Ot[(rl0 + j) * 136 + cl] = f2b(tanh_fast(f) + f * (1.f - hh * hh));
          }
        }
      }
    }
    __syncthreads();
    #pragma unroll
    for (int sub = 0; sub < 2; ++sub) {
      const int rl0 = wid * 32 + sub * 16;
      f32x4 pacc = (f32x4){0.f, 0.f, 0.f, 0.f};
      #pragma unroll
      for (int ks = 0; ks < 4; ++ks) {
        short8 afrag = *(const short8*)(Ot + (rl0 + fr) * 136 + ks * 32 + kg * 8);
        short8 bfrag = *(const short8*)(Wn + fr * 1024 + col0 + ks * 32 + kg * 8);
        pacc = __builtin_amdgcn_mfma_f32_16x16x32_bf16(afrag, bfrag, pacc, 0, 0, 0);
      }
      #pragma unroll
      for (int j = 0; j < 4; ++j)
        Pp[((long)blockIdx.y * ckRows + row0 + rl0 + kg * 4 + j) * 16 + fr] = pacc[j];
    }
  }
}

// ---------------- k7: out = J*(sum_cb(Pp0+Pp1) + bff) ----------------------
__global__ __launch_bounds__(256) void k7(
    const float* __restrict__ Pp0, const float* __restrict__ Pp1,
    const float* __restrict__ bff, float* __restrict__ out,
    long grow0, int ckRows)
{
  int i = blockIdx.x * 256 + threadIdx.x;
  int r = i >> 4, j = i & 15, jp = (j + 8) & 15;
  float s = bff[jp];
  #pragma unroll
  for (int cb = 0; cb < 8; ++cb) {
    long o = ((long)cb * ckRows + r) * 16 + jp;
    s += Pp0[o] + Pp1[o];
  }
  out[(grow0 + r) * 16 + j] = (j < 8) ? s : -s;
}

// ---------------- host ----------------
extern "C" void kernel_launch(void* const* d_in, const int* in_sizes, int n_in,
                              void* d_out, int out_size, void* d_ws, size_t ws_size,
                              hipStream_t stream) {
  const float* z   = (const float*)d_in[1];
  const float* W1  = (const float*)d_in[2];
  const float* b1  = (const float*)d_in[3];
  const float* W2  = (const float*)d_in[4];
  const float* b2  = (const float*)d_in[5];
  const float* Wh  = (const float*)d_in[6];
  const float* Wf1 = (const float*)d_in[8];
  const float* bf1 = (const float*)d_in[9];
  const float* Wf2 = (const float*)d_in[10];
  const float* bf2 = (const float*)d_in[11];
  const float* Wff = (const float*)d_in[12];
  const float* bff = (const float*)d_in[13];
  const float* Wp  = (const float*)d_in[14];
  const float* bp  = (const float*)d_in[15];
  float* out = (float*)d_out;
  const int N = in_sizes[1] / 16;

  char* p = (char*)d_ws;
  auto alloc = [&](size_t bytes) {
    char* q = p; p += (bytes + 255) & ~(size_t)255; return q;
  };
  bf16* W2bf  = (bf16*)alloc(1024 * 1024 * 2);
  bf16* W2Tbf = (bf16*)alloc(1024 * 1024 * 2);
  bf16* Wf2bf = (bf16*)alloc(1024 * 1024 * 2);
  bf16* W1n   = (bf16*)alloc(16 * 1024 * 2);
  bf16* Wffn  = (bf16*)alloc(16 * 1024 * 2);
  bf16* Wf1p  = (bf16*)alloc(1024 * 32 * 2);
  size_t wbytes = (size_t)(p - (char*)d_ws);

  int CK = N;  // chunk rows (power of two, divides N)
  // per-row: 3 bf16 act buffers (3*2048 B) + 2 Pp f32 partial sets (2*512 B)
  while (CK > 128 && wbytes + (size_t)CK * 7168 > ws_size) CK >>= 1;
  bf16* actA = (bf16*)alloc((size_t)CK * 2048);          // h1
  bf16* actB = (bf16*)alloc((size_t)CK * 2048);          // gb
  bf16* actD = (bf16*)alloc((size_t)CK * 2048);          // g1f
  float* Pp0 = (float*)alloc((size_t)CK * 8 * 16 * 4);   // gemm1 partials
  float* Pp1 = (float*)alloc((size_t)CK * 8 * 16 * 4);   // gemm2 partials

  prep<<<1024, 256, 0, stream>>>(W2, Wf2, W1, Wff, Wf1,
                                 W2bf, W2Tbf, Wf2bf, W1n, Wffn, Wf1p);

  for (long r0 = 0; r0 < N; r0 += CK) {
    k1<<<CK / 32, 256, 0, stream>>>(z, W1, b1, actA, r0);
    gemm_k<0><<<dim3(CK / 128, 8), 256, 0, stream>>>(
        actA, W2bf, b2, Wh, nullptr, actD, actB,
        z, Wp, bp, bf1, Wf1p, nullptr, nullptr, r0, CK);
    gemm_k<1><<<dim3(CK / 128, 8), 256, 0, stream>>>(
        actB, W2Tbf, nullptr, nullptr, actA, nullptr, nullptr,
        nullptr, nullptr, nullptr, nullptr, nullptr, W1n, Pp0, r0, CK);
    gemm_k<2><<<dim3(CK / 128, 8), 256, 0, stream>>>(
        actD, Wf2bf, bf2, nullptr, actA, nullptr, nullptr,
        nullptr, nullptr, nullptr, nullptr, nullptr, Wffn, Pp1, r0, CK);
    k7<<<CK / 16, 256, 0, stream>>>(Pp0, Pp1, bff, out, r0, CK);
  }
}